// Round 13
// baseline (151.947 us; speedup 1.0000x reference)
//
#include <hip/hip_runtime.h>
#include <math.h>

#define B 8
#define T 128
#define NKEY 127   // t-1
#define NPAD 128   // padded key count (score row 127 forced to prob 0)
#define KDIM 64    // Q_DIM == KV_DIM
#define NH 4       // heads
#define CH 256     // NH*KDIM output channels

typedef short short8 __attribute__((ext_vector_type(8)));   // 8 bf16 (4 VGPRs)
typedef float floatx4 __attribute__((ext_vector_type(4)));  // MFMA C/D

// tanh(x) = 1 - 2/(e^{2x}+1). Saturates correctly at +/-inf, no clamp needed.
__device__ __forceinline__ float fast_tanh(float x) {
    float e = __expf(2.f * x);
    float r = __builtin_amdgcn_rcpf(e + 1.f);
    return fmaf(-2.f, r, 1.f);
}

// Round-to-nearest-even bf16 x8 (hi-only path for both A and B fragments).
__device__ __forceinline__ void rne8(const float4& a, const float4& b, short8& hi) {
    float x[8] = {a.x, a.y, a.z, a.w, b.x, b.y, b.z, b.w};
    #pragma unroll
    for (int i = 0; i < 8; ++i) {
        unsigned u = __float_as_uint(x[i]);
        u += 0x7FFFu + ((u >> 16) & 1u);
        hi[i] = (short)(u >> 16);
    }
}

// One block per (bt, head): 4096 blocks x 256 threads, XCD-SWIZZLED.
// R13 = R11 (best TLP profile: VGPR 44, occupancy 47%, small phase-diverse
// blocks) + XCD-aware blockIdx swizzle. R11's sole failure: the 4 head-blocks
// of one bt landed on different XCDs (round-robin dispatch), each filling its
// own non-coherent L2 -> FETCH 116 MB, ~60 us of L2-fill traffic. Swizzle:
// XCD = blockIdx%8 (heuristic), so decode bt/h such that all 4 heads of a bt
// share i%8 (same XCD) and are dispatched within 32 block IDs:
//   i = 32*m + 8*h + xcd  ->  bt = xcd*128 + m.  Per-XCD resident kv working
// set ~2 MB < 4 MB L2. R12's lesson applied: keep 4-wave blocks (8-wave
// blocks serialize on barriers); launch_bounds arg2=2 (arg2>2 spills).
__global__ __launch_bounds__(256, 2)
void attn_kernel(const float* __restrict__ q_x,   // (B,T,64)
                 const float* __restrict__ kv_x,  // (B,T,127,64)
                 const float* __restrict__ Wk,    // (256,64)
                 const float* __restrict__ Wq,    // (256,64)
                 const float* __restrict__ Wv,    // (256,64)
                 const float* __restrict__ bias,  // (64,)
                 const float* __restrict__ Ws,    // (1,64)
                 const float* __restrict__ bs,    // (1,) -- cancels in softmax
                 float* __restrict__ out)         // (B,T,256)
{
    __shared__ __align__(16) short bh_lds[16][64][8];   // 16 KB: B-frag hi [chunk][lane][8]
    __shared__ float qb_lds[KDIM];                      // 256 B: query+bias (this head)
    __shared__ float p_lds[NPAD];                       // 512 B: scores then probs
    __shared__ __align__(16) float part_lds[4][KDIM];   // 1 KB: Phase-B partials
    __shared__ float invl_lds;                          // -> ~17.8 KB total

    // ---- XCD-aware decode: i = 32m + 8h + xcd; bt = xcd*128 + m ----
    const int idx  = blockIdx.x;           // 0..4095
    const int xcd  = idx & 7;              // assumed XCD (round-robin %8)
    const int hm   = idx >> 3;             // 0..511
    const int h    = hm & 3;               // this block's head
    const int bt   = xcd * 128 + (hm >> 2);
    const int tid  = threadIdx.x;          // 0..255
    const int wv   = tid >> 6;             // wave 0..3
    const int lane = tid & 63;
    const int col  = lane & 15;            // MFMA n/m lane index
    const int quad = lane >> 4;            // MFMA k-group / row-group

    const float* __restrict__ kvg = kv_x + (size_t)bt * NKEY * KDIM;

    // ---- convert kv (global/L2-shared) -> fragment-ordered bf16-hi LDS ----
    // chunk = nt*2+ks; write addr chunk*1024 + lane*16: lane-linear, 0 conflicts.
    // Fragment content: kv[nt*16 + col][ks*32 + quad*8 + j]
    #pragma unroll
    for (int c = 0; c < 4; ++c) {
        const int chunk = c * 4 + wv;
        const int nt = chunk >> 1, ks = chunk & 1;
        const int n  = nt * 16 + col;
        const int k0 = ks * 32 + quad * 8;
        float4 a = make_float4(0.f, 0.f, 0.f, 0.f);
        float4 b = make_float4(0.f, 0.f, 0.f, 0.f);
        if (n < NKEY) {
            const float* p = kvg + (size_t)n * KDIM + k0;
            a = *(const float4*)p;
            b = *(const float4*)(p + 4);
        }
        short8 hi;
        rne8(a, b, hi);
        *(short8*)&bh_lds[chunk][lane][0] = hi;
    }

    // ---- qb for this head's 64 channels: wave wv does channels wv*16+col,
    //      k-quad = quad (16 k each), cross-quad shuffle reduce ----
    {
        const int c = wv * 16 + col;                     // channel within head
        const float* wrow = Wq + (size_t)(h * 64 + c) * KDIM + quad * 16;
        const float* qrow = q_x + (size_t)bt * KDIM + quad * 16;
        float s = 0.f;
        #pragma unroll
        for (int i = 0; i < 4; ++i) {
            float4 ww = ((const float4*)wrow)[i];
            float4 qq = ((const float4*)qrow)[i];
            s = fmaf(qq.x, ww.x, s); s = fmaf(qq.y, ww.y, s);
            s = fmaf(qq.z, ww.z, s); s = fmaf(qq.w, ww.w, s);
        }
        s += __shfl_xor(s, 16, 64);
        s += __shfl_xor(s, 32, 64);
        if (lane < 16) qb_lds[c] = s + bias[c];
    }

    __syncthreads();   // B1: frags + qb ready

    // ---- scores for nt = wv*2, wv*2+1; jt in 2 passes of 2 ----
    float sp[2] = {0.f, 0.f};
    #pragma unroll
    for (int pass = 0; pass < 2; ++pass) {
        short8 ahi[2][2];
        float qbp[2][4], wsp[2][4];
        #pragma unroll
        for (int jj = 0; jj < 2; ++jj) {
            const int jt = pass * 2 + jj;
            #pragma unroll
            for (int ks = 0; ks < 2; ++ks) {
                const float* wrow = Wk + (size_t)(h * 64 + jt * 16 + col) * KDIM
                                       + ks * 32 + quad * 8;
                float4 a = *(const float4*)wrow;
                float4 b = *(const float4*)(wrow + 4);
                rne8(a, b, ahi[jj][ks]);
            }
            #pragma unroll
            for (int r = 0; r < 4; ++r) {
                const int j = jt * 16 + quad * 4 + r;
                qbp[jj][r] = qb_lds[j];
                wsp[jj][r] = Ws[j];
            }
        }
        #pragma unroll
        for (int ntl = 0; ntl < 2; ++ntl) {
            const int nt = wv * 2 + ntl;
            short8 b0 = *(const short8*)&bh_lds[nt * 2 + 0][lane][0];
            short8 b1 = *(const short8*)&bh_lds[nt * 2 + 1][lane][0];
            #pragma unroll
            for (int jj = 0; jj < 2; ++jj) {
                floatx4 c = {0.f, 0.f, 0.f, 0.f};
                c = __builtin_amdgcn_mfma_f32_16x16x32_bf16(ahi[jj][0], b0, c, 0, 0, 0);
                c = __builtin_amdgcn_mfma_f32_16x16x32_bf16(ahi[jj][1], b1, c, 0, 0, 0);
                // D layout: col = n in tile, row = quad*4 + r = j in jt
                #pragma unroll
                for (int r = 0; r < 4; ++r)
                    sp[ntl] = fmaf(fast_tanh(c[r] + qbp[jj][r]), wsp[jj][r], sp[ntl]);
            }
        }
    }
    #pragma unroll
    for (int ntl = 0; ntl < 2; ++ntl) {
        float s = sp[ntl];
        s += __shfl_xor(s, 16, 64);   // reduce across quads (same col)
        s += __shfl_xor(s, 32, 64);
        if (lane < 16) p_lds[(wv * 2 + ntl) * 16 + col] = s;
    }

    __syncthreads();   // B2: all 128 scores visible

    // ---- softmax over 127 real keys (wave 0; 2 scores per lane) ----
    if (wv == 0) {
        float s_a = p_lds[lane];
        float s_b = p_lds[64 + lane];
        if (lane == 63) s_b = -1e30f;          // mask pad row 127
        float mx = fmaxf(s_a, s_b);
        #pragma unroll
        for (int off = 32; off > 0; off >>= 1)
            mx = fmaxf(mx, __shfl_xor(mx, off, 64));
        float pa = __expf(s_a - mx);
        float pb = __expf(s_b - mx);           // lane 63 -> 0
        float ls = pa + pb;
        #pragma unroll
        for (int off = 32; off > 0; off >>= 1)
            ls += __shfl_xor(ls, off, 64);
        p_lds[lane]      = pa;                 // unnormalized probs
        p_lds[64 + lane] = pb;                 // p_lds[127] = 0 masks pad
        if (lane == 0) invl_lds = 1.f / ls;
    }

    __syncthreads();   // B3: probs + invl visible

    // ---- Phase B: wave wv accumulates rows n = 32wv + 4i + quad over k=4col..4col+3
    //      (coalesced dwordx4 from global, L2-hot; probs broadcast from LDS) ----
    {
        float4 a4 = make_float4(0.f, 0.f, 0.f, 0.f);
        #pragma unroll
        for (int i = 0; i < 8; ++i) {
            const int n = 32 * wv + 4 * i + quad;
            const int n_eff = (n < NKEY) ? n : 0;      // row 127: p==0
            float4 v = *(const float4*)&kvg[(size_t)n_eff * KDIM + 4 * col];
            const float pn = p_lds[n];
            a4.x = fmaf(pn, v.x, a4.x);
            a4.y = fmaf(pn, v.y, a4.y);
            a4.z = fmaf(pn, v.z, a4.z);
            a4.w = fmaf(pn, v.w, a4.w);
        }
        a4.x += __shfl_xor(a4.x, 16, 64);  a4.y += __shfl_xor(a4.y, 16, 64);
        a4.z += __shfl_xor(a4.z, 16, 64);  a4.w += __shfl_xor(a4.w, 16, 64);
        a4.x += __shfl_xor(a4.x, 32, 64);  a4.y += __shfl_xor(a4.y, 32, 64);
        a4.z += __shfl_xor(a4.z, 32, 64);  a4.w += __shfl_xor(a4.w, 32, 64);
        if (lane < 16)
            *(float4*)&part_lds[wv][4 * col] = a4;      // unnormalized
    }

    __syncthreads();   // B4: partials ready

    // ---- Phase C: wave wv -> channels wv*16+col; k-quad split, shuffle reduce ----
    {
        const int c = wv * 16 + col;                    // channel within head
        const float inv = invl_lds;
        const float* wrow = Wv + (size_t)(h * 64 + c) * KDIM + quad * 16;
        float s = 0.f;
        #pragma unroll
        for (int i = 0; i < 4; ++i) {
            // wkv_unnorm[k] = sum over 4 wave-partials
            float4 p0 = ((const float4*)&part_lds[0][quad * 16])[i];
            float4 p1 = ((const float4*)&part_lds[1][quad * 16])[i];
            float4 p2 = ((const float4*)&part_lds[2][quad * 16])[i];
            float4 p3 = ((const float4*)&part_lds[3][quad * 16])[i];
            float4 ww = ((const float4*)wrow)[i];
            s = fmaf((p0.x + p1.x) + (p2.x + p3.x), ww.x, s);
            s = fmaf((p0.y + p1.y) + (p2.y + p3.y), ww.y, s);
            s = fmaf((p0.z + p1.z) + (p2.z + p3.z), ww.z, s);
            s = fmaf((p0.w + p1.w) + (p2.w + p3.w), ww.w, s);
        }
        s += __shfl_xor(s, 16, 64);
        s += __shfl_xor(s, 32, 64);
        if (lane < 16)
            out[(size_t)bt * CH + h * 64 + c] = s * inv;
    }
}

extern "C" void kernel_launch(void* const* d_in, const int* in_sizes, int n_in,
                              void* d_out, int out_size, void* d_ws, size_t ws_size,
                              hipStream_t stream) {
    const float* q_x  = (const float*)d_in[0];
    const float* kv_x = (const float*)d_in[1];
    const float* Wk   = (const float*)d_in[2];
    const float* Wq   = (const float*)d_in[3];
    const float* Wv   = (const float*)d_in[4];
    const float* bias = (const float*)d_in[5];
    const float* Ws   = (const float*)d_in[6];
    const float* bs   = (const float*)d_in[7];
    float* out = (float*)d_out;

    attn_kernel<<<dim3(B * T * NH), dim3(256), 0, stream>>>(
        q_x, kv_x, Wk, Wq, Wv, bias, Ws, bs, out);
}